// Round 4
// baseline (180.173 us; speedup 1.0000x reference)
//
#include <hip/hip_runtime.h>
#include <math.h>

// Cosine similarity per matching row: out[r] = dot(a[r,:], b[r,:]) /
// (||a[r,:]|| * ||b[r,:]||), D = 256 floats per row, eps-guarded.
//
// Round-8 = round-7 resubmitted verbatim (round-7 hit an infra failure:
// "MI355X container failed twice"; kernel never executed).
//
// Round-7 rationale: discriminate "per-direction fabric cap (~3.2-3.4 TB/s)"
// vs "DS-chain reduction cost".
// Evidence so far: 2-deep/58%-occ (r5), 16-deep-asm/38%-occ (r6) both 3.0 TB/s;
// nt variant (r4) 3.36 TB/s. MLP and occupancy are NOT the limiter. m13's
// 6.29 TB/s "achievable" is a copy = 3.15R + 3.15W -> per-direction budget.
// Infinity Cache is memory-attached (MALL): L3 hits cross the same fabric
// port as HBM, so the 50% hit mix can't help.
// This version = round-4's best memory config + 16x cheaper reduction:
//  - nt loads (best measured read config, ~3.36 TB/s),
//  - 8 lanes per row: each lane FMA-accumulates 32 consecutive floats
//    (8 x f4), so the dot products ride the VALU and overlap the loads,
//  - all 8 rows of the wave reduce in the SAME 3 shuffle levels
//    (9 DS ops/wave vs 144 in rounds 4-6),
//  - plain __launch_bounds__(256): 8 waves/SIMD, VGPR stays ~48.
// Prediction: ~40us => fabric cap confirmed (declare roofline next round);
// 34-37us => DS chain was additive, keep mining.

#define EPS 1e-12f

typedef float f4 __attribute__((ext_vector_type(4)));

__global__ __launch_bounds__(256) void cosine_rows_kernel(
    const float* __restrict__ a,
    const float* __restrict__ b,
    float* __restrict__ out,
    int nrows)
{
    const int lane = threadIdx.x & 63;
    const int wid  = (blockIdx.x << 2) + (threadIdx.x >> 6);
    const int nw   = gridDim.x << 2;
    const int sub  = lane & 7;   // lane's position within its row-group
    const int rloc = lane >> 3;  // which of the wave's 8 rows

    for (int base = wid * 8; base < nrows; base += nw * 8) {
        const int row = base + rloc;
        // lane covers floats [sub*32, sub*32+32) of its row; 16B aligned
        const f4* ap = (const f4*)(a + (size_t)row * 256 + sub * 32);
        const f4* bp = (const f4*)(b + (size_t)row * 256 + sub * 32);

        float saa = 0.f, sbb = 0.f, sab = 0.f;
        #pragma unroll
        for (int j = 0; j < 8; ++j) {
            f4 av = __builtin_nontemporal_load(&ap[j]);
            f4 bv = __builtin_nontemporal_load(&bp[j]);
            saa += av.x * av.x + av.y * av.y + av.z * av.z + av.w * av.w;
            sbb += bv.x * bv.x + bv.y * bv.y + bv.z * bv.z + bv.w * bv.w;
            sab += av.x * bv.x + av.y * bv.y + av.z * bv.z + av.w * bv.w;
        }

        // 8-lane-group butterfly: all 8 rows reduce in the same 3 levels.
        #pragma unroll
        for (int off = 4; off > 0; off >>= 1) {
            saa += __shfl_xor(saa, off, 64);
            sbb += __shfl_xor(sbb, off, 64);
            sab += __shfl_xor(sab, off, 64);
        }

        if (sub == 0) {
            const float denom = sqrtf(fmaxf(saa, EPS)) * sqrtf(fmaxf(sbb, EPS));
            out[row] = sab / denom;
        }
    }
}

extern "C" void kernel_launch(void* const* d_in, const int* in_sizes, int n_in,
                              void* d_out, int out_size, void* d_ws, size_t ws_size,
                              hipStream_t stream) {
    const float* a = (const float*)d_in[0];
    const float* b = (const float*)d_in[1];
    float* out = (float*)d_out;

    const int nrows = out_size;   // 16 * 4096 = 65536 (divisible by 8)
    const int blocks = 2048;      // 8192 waves x 8 rows = 65536: one shot

    cosine_rows_kernel<<<blocks, 256, 0, stream>>>(a, b, out, nrows);
}

// Round 5
// 136.696 us; speedup vs baseline: 1.3181x; 1.3181x over previous
//
#include <hip/hip_runtime.h>
#include <math.h>

// Cosine similarity per matching row: out[r] = dot(a[r,:], b[r,:]) /
// (||a[r,:]|| * ||b[r,:]||), D = 256 floats per row, eps-guarded.
//
// Round-9: restore round-0/round-4 best (136.8us scored, kernel <=40.4us) —
// verbatim. Rationale from the session's counter evidence:
//  - Read path beyond-L2 caps at ~3.3-3.4 TB/s chip-wide (per-XCD fabric
//    read budget ~420 GB/s x 8). Evidence: 2-deep/58%occ, 16-deep-asm/38%occ,
//    nt, and strided-nt kernels ALL land at 2.8-3.4 TB/s read, while the
//    harness fills sustain 6.58 TB/s WRITE-only, and 50% L3-hit service
//    (r5) did not raise effective read BW at all (L3 is memory-side MALL).
//  - This kernel is a single-pass streaming reduce: 134.2 MB irreducible
//    reads -> floor ~40us. This config measured at/below 40.4us = at floor.
//  - MLP (r6), occupancy (r6), reduction cost (r5 vs r6), L3 residency (r5)
//    each independently falsified as levers.
//  - Coalescing is mandatory: r8's per-lane-serial layout (wave footprint
//    strided 128B) cost 1.46x over-fetch and 72.5us.

#define EPS 1e-12f

typedef float f4 __attribute__((ext_vector_type(4)));

__global__ __launch_bounds__(256) void cosine_rows_kernel(
    const f4* __restrict__ a4,
    const f4* __restrict__ b4,
    float* __restrict__ out,
    int nrows)
{
    const int lane = threadIdx.x & 63;
    const int wid  = (blockIdx.x << 2) + (threadIdx.x >> 6);
    const int nw   = gridDim.x << 2;

    for (int base = wid * 4; base < nrows; base += nw * 4) {
        // 8 independent 1 KiB wave-loads, all issued before any use.
        const int i0 = (base + 0) * 64 + lane;
        const int i1 = (base + 1) * 64 + lane;
        const int i2 = (base + 2) * 64 + lane;
        const int i3 = (base + 3) * 64 + lane;
        f4 av0 = __builtin_nontemporal_load(&a4[i0]);
        f4 av1 = __builtin_nontemporal_load(&a4[i1]);
        f4 av2 = __builtin_nontemporal_load(&a4[i2]);
        f4 av3 = __builtin_nontemporal_load(&a4[i3]);
        f4 bv0 = __builtin_nontemporal_load(&b4[i0]);
        f4 bv1 = __builtin_nontemporal_load(&b4[i1]);
        f4 bv2 = __builtin_nontemporal_load(&b4[i2]);
        f4 bv3 = __builtin_nontemporal_load(&b4[i3]);

        f4 avs[4] = {av0, av1, av2, av3};
        f4 bvs[4] = {bv0, bv1, bv2, bv3};

        #pragma unroll
        for (int r = 0; r < 4; ++r) {
            const f4 av = avs[r];
            const f4 bv = bvs[r];
            float saa = av.x * av.x + av.y * av.y + av.z * av.z + av.w * av.w;
            float sbb = bv.x * bv.x + bv.y * bv.y + bv.z * bv.z + bv.w * bv.w;
            float sab = av.x * bv.x + av.y * bv.y + av.z * bv.z + av.w * bv.w;

            #pragma unroll
            for (int off = 32; off > 0; off >>= 1) {
                saa += __shfl_xor(saa, off, 64);
                sbb += __shfl_xor(sbb, off, 64);
                sab += __shfl_xor(sab, off, 64);
            }

            if (lane == 0) {
                const float denom = sqrtf(fmaxf(saa, EPS)) * sqrtf(fmaxf(sbb, EPS));
                out[base + r] = sab / denom;
            }
        }
    }
}

extern "C" void kernel_launch(void* const* d_in, const int* in_sizes, int n_in,
                              void* d_out, int out_size, void* d_ws, size_t ws_size,
                              hipStream_t stream) {
    const float* a = (const float*)d_in[0];
    const float* b = (const float*)d_in[1];
    float* out = (float*)d_out;

    const int nrows = out_size;   // 16 * 4096 = 65536 (divisible by 4)
    const int blocks = 2048;      // 8 blocks/CU target; 2 sweeps per wave

    cosine_rows_kernel<<<blocks, 256, 0, stream>>>(
        (const f4*)a, (const f4*)b, out, nrows);
}